// Round 6
// baseline (160.640 us; speedup 1.0000x reference)
//
#include <hip/hip_runtime.h>
#include <hip/hip_bf16.h>

// TripletLoss B=4096 D=128 fp32. R6: two launches.
// prep: f32->bf16 convert + row norms + zero counters.
// fused: 128x128 bf16 MFMA Gram tile/block (grid 1024), full K=128 in LDS,
//   raw s_barrier + fine vmcnt, XOR-swizzled LDS (conflict-free b128),
//   mine val = sq[j]-2g, LDS-fold -> per-(jblock,row) partial stores,
//   release-ticket; last 16 tickets spin (acquire) then fold 32 partials/row,
//   validity from sentinels (mp>-BIG && mn<+BIG == any(pos)&&any(neg) —
//   no label histogram needed), sqrt, reduce, ticket2 finalize.

typedef __attribute__((ext_vector_type(8))) short short8;
typedef __attribute__((ext_vector_type(4))) float f32x4;

#define MARGIN_F 0.3f
#define NEG_BIG -3.4e38f
#define POS_BIG 3.4e38f
// gfx9 waitcnt encoding: vmcnt[3:0]|[15:14], expcnt[6:4], lgkmcnt[11:8]
#define WAITVM(N) __builtin_amdgcn_s_waitcnt(((N)&15)|((((N)>>4)&3)<<14)|(7<<4)|(15<<8))

__device__ __forceinline__ void gl_lds16(const void* g, void* l) {
    __builtin_amdgcn_global_load_lds(
        (const __attribute__((address_space(1))) void*)g,
        (__attribute__((address_space(3))) void*)l, 16, 0, 0);
}

__device__ inline unsigned short f2bf(float x) {
    union { __hip_bfloat16 h; unsigned short u; } c;
    c.h = __float2bfloat16(x);
    return c.u;
}

// grid 512 x 256: 32 threads/row. bf16 convert + row norms + zero counters.
__global__ __launch_bounds__(256) void tl_prep(const float* __restrict__ E,
                                               unsigned short* __restrict__ Ebf,
                                               float* __restrict__ sqn,
                                               unsigned* __restrict__ cnt) {
    int t = blockIdx.x * 256 + threadIdx.x;
    if (t < 4) cnt[t] = 0u;  // [0]=sum,[1]=nvalid,[2]=ticket2,[3]=done
    int row = t >> 5;
    int kq = (t & 31) * 4;
    float4 v = *(const float4*)&E[(size_t)row * 128 + kq];
    float s = fmaf(v.x, v.x, fmaf(v.y, v.y, fmaf(v.z, v.z, v.w * v.w)));
    ushort4 h4;
    h4.x = f2bf(v.x); h4.y = f2bf(v.y); h4.z = f2bf(v.z); h4.w = f2bf(v.w);
    *(ushort4*)&Ebf[(size_t)row * 128 + kq] = h4;
#pragma unroll
    for (int m = 1; m < 32; m <<= 1) s += __shfl_xor(s, m);
    if ((t & 31) == 0) sqn[row] = s;
}

// grid (32,32) x 256. 4 waves 2x2, wave tile 64x64 = 4x4 MFMA 16x16x32.
__global__ __launch_bounds__(256, 2) void tl_fused(const unsigned short* __restrict__ Ebf,
                                                   const int* __restrict__ labels,
                                                   const float* __restrict__ sqn,
                                                   float* __restrict__ pmp,
                                                   float* __restrict__ pmn,
                                                   unsigned* __restrict__ cnt,
                                                   float* __restrict__ accum,
                                                   float* __restrict__ out) {
    union SM {
        struct { unsigned short A[2][128 * 64]; unsigned short B[2][128 * 64]; } s;
        struct { float mp[128][32]; float mn[128][32]; } f;
    };
    __shared__ __align__(16) SM sm;
    __shared__ unsigned tkt;

    const int tid = threadIdx.x;
    const int l = tid & 63, w = tid >> 6;
    const int wr = w >> 1, wc = w & 1;
    const int q = l >> 4, r16 = l & 15;
    const int i0 = blockIdx.x * 128, j0 = blockIdx.y * 128;

    const unsigned short* gA[4];
    const unsigned short* gB[4];
#pragma unroll
    for (int t2 = 0; t2 < 4; ++t2) {
        int s = w * 256 + t2 * 64 + l;
        int row = s >> 3, ch = (s & 7) ^ (row & 7);
        gA[t2] = Ebf + (size_t)(i0 + row) * 128 + ch * 8;
        gB[t2] = Ebf + (size_t)(j0 + row) * 128 + ch * 8;
    }

    int li[4][4], lj[4];
    float sj[4];
#pragma unroll
    for (int ti = 0; ti < 4; ++ti)
#pragma unroll
        for (int p = 0; p < 4; ++p)
            li[ti][p] = labels[i0 + wr * 64 + ti * 16 + q * 4 + p];
#pragma unroll
    for (int tj = 0; tj < 4; ++tj) {
        int cj = j0 + wc * 64 + tj * 16 + r16;
        lj[tj] = labels[cj];
        sj[tj] = sqn[cj];
    }

#pragma unroll
    for (int t2 = 0; t2 < 4; ++t2) {
        gl_lds16(gA[t2], &sm.s.A[0][w * 2048 + t2 * 512]);
        gl_lds16(gB[t2], &sm.s.B[0][w * 2048 + t2 * 512]);
    }
#pragma unroll
    for (int t2 = 0; t2 < 4; ++t2) {
        gl_lds16(gA[t2] + 64, &sm.s.A[1][w * 2048 + t2 * 512]);
        gl_lds16(gB[t2] + 64, &sm.s.B[1][w * 2048 + t2 * 512]);
    }

    f32x4 acc[4][4];
#pragma unroll
    for (int ti = 0; ti < 4; ++ti)
#pragma unroll
        for (int tj = 0; tj < 4; ++tj) acc[ti][tj] = (f32x4)0.0f;

#pragma unroll
    for (int kc = 0; kc < 2; ++kc) {
        if (kc == 0) WAITVM(8); else WAITVM(0);
        __builtin_amdgcn_s_barrier();
#pragma unroll
        for (int s = 0; s < 2; ++s) {
            short8 af[4], bf[4];
            const int cA = ((s * 4 + q) ^ (r16 & 7)) * 8;
#pragma unroll
            for (int t2 = 0; t2 < 4; ++t2) {
                af[t2] = *(const short8*)&sm.s.A[kc][(wr * 64 + t2 * 16 + r16) * 64 + cA];
                bf[t2] = *(const short8*)&sm.s.B[kc][(wc * 64 + t2 * 16 + r16) * 64 + cA];
            }
#pragma unroll
            for (int ti = 0; ti < 4; ++ti)
#pragma unroll
                for (int tj = 0; tj < 4; ++tj)
                    acc[ti][tj] = __builtin_amdgcn_mfma_f32_16x16x32_bf16(
                        af[ti], bf[tj], acc[ti][tj], 0, 0, 0);
        }
    }

    // mine val = sq[j] - 2*g (monotone in d2 for fixed i)
    float mp[4][4], mn[4][4];
#pragma unroll
    for (int ti = 0; ti < 4; ++ti)
#pragma unroll
        for (int p = 0; p < 4; ++p) { mp[ti][p] = NEG_BIG; mn[ti][p] = POS_BIG; }
    const bool diagblk = (blockIdx.x == blockIdx.y);
#pragma unroll
    for (int tj = 0; tj < 4; ++tj) {
#pragma unroll
        for (int ti = 0; ti < 4; ++ti)
#pragma unroll
            for (int p = 0; p < 4; ++p) {
                float val = fmaf(-2.0f, acc[ti][tj][p], sj[tj]);
                bool same = (li[ti][p] == lj[tj]);
                bool self = diagblk &&
                    ((wr * 64 + ti * 16 + q * 4 + p) == (wc * 64 + tj * 16 + r16));
                mp[ti][p] = fmaxf(mp[ti][p], (same && !self) ? val : NEG_BIG);
                mn[ti][p] = fminf(mn[ti][p], same ? POS_BIG : val);
            }
    }

    __syncthreads();  // frag reads done before aliasing overwrite
#pragma unroll
    for (int ti = 0; ti < 4; ++ti)
#pragma unroll
        for (int p = 0; p < 4; ++p) {
            int rloc = wr * 64 + ti * 16 + q * 4 + p;
            sm.f.mp[rloc][wc * 16 + r16] = mp[ti][p];
            sm.f.mn[rloc][wc * 16 + r16] = mn[ti][p];
        }
    __syncthreads();
    if (tid < 128) {
        int row = tid;
        const float4* P = (const float4*)&sm.f.mp[row][0];
        const float4* N = (const float4*)&sm.f.mn[row][0];
        float M = NEG_BIG, m_ = POS_BIG;
#pragma unroll
        for (int k = 0; k < 8; ++k) {
            float4 p4 = P[k], n4 = N[k];
            M = fmaxf(M, fmaxf(fmaxf(p4.x, p4.y), fmaxf(p4.z, p4.w)));
            m_ = fminf(m_, fminf(fminf(n4.x, n4.y), fminf(n4.z, n4.w)));
        }
        pmp[(size_t)blockIdx.y * 4096 + i0 + row] = M;
        pmn[(size_t)blockIdx.y * 4096 + i0 + row] = m_;
    }

    // ---- ticket: am I one of the last 16 blocks? ----
    __syncthreads();  // drains vmcnt: partial stores issued to L2
    __threadfence();  // agent-scope release: write back L2 (all waves)
    if (tid == 0)
        tkt = __hip_atomic_fetch_add(&cnt[3], 1u, __ATOMIC_ACQ_REL,
                                     __HIP_MEMORY_SCOPE_AGENT);
    __syncthreads();
    unsigned my = tkt;
    if (my < 1008u) return;

    // ---- tail: spin until all 1024 blocks done ----
    if (tid == 0) {
        while (__hip_atomic_load(&cnt[3], __ATOMIC_ACQUIRE,
                                 __HIP_MEMORY_SCOPE_AGENT) < 1024u)
            __builtin_amdgcn_s_sleep(16);
    }
    __syncthreads();
    __threadfence();  // acquire: invalidate stale L2/L1 lines

    int r = (int)(my - 1008u) * 256 + tid;
    float fmp = NEG_BIG, fmn = POS_BIG;
#pragma unroll
    for (int k = 0; k < 32; ++k) {
        fmp = fmaxf(fmp, pmp[(size_t)k * 4096 + r]);
        fmn = fminf(fmn, pmn[(size_t)k * 4096 + r]);
    }
    float si = sqn[r];
    bool valid = (fmp > 0.5f * NEG_BIG) && (fmn < 0.5f * POS_BIG);
    float hp = sqrtf(fmaxf(si + fmp, 0.0f));
    float hn = sqrtf(fmaxf(si + fmn, 0.0f));
    float pr = fmaxf(hp - hn + MARGIN_F, 0.0f);
    float s = valid ? pr : 0.0f;
    float n = valid ? 1.0f : 0.0f;
#pragma unroll
    for (int m = 1; m < 64; m <<= 1) {
        s += __shfl_xor(s, m);
        n += __shfl_xor(n, m);
    }
    __shared__ float sp[4], sv[4];
    if ((tid & 63) == 0) { sp[tid >> 6] = s; sv[tid >> 6] = n; }
    __syncthreads();
    if (tid == 0) {
        atomicAdd(&accum[0], sp[0] + sp[1] + sp[2] + sp[3]);
        atomicAdd(&accum[1], sv[0] + sv[1] + sv[2] + sv[3]);
        __threadfence();
        unsigned tk2 = atomicAdd(&cnt[2], 1u);
        if (tk2 == 15u) {
            float a = atomicAdd(&accum[0], 0.0f);  // coherent read
            float b = atomicAdd(&accum[1], 0.0f);
            out[0] = a / fmaxf(b, 1.0f);
        }
    }
}

extern "C" void kernel_launch(void* const* d_in, const int* in_sizes, int n_in,
                              void* d_out, int out_size, void* d_ws, size_t ws_size,
                              hipStream_t stream) {
    const float* E = (const float*)d_in[0];
    const int* labels = (const int*)d_in[1];
    float* out = (float*)d_out;

    // ws: Ebf 1 MB | pmp 512 KB | pmn 512 KB | sqn 16 KB | cnt/accum
    char* base = (char*)d_ws;
    unsigned short* Ebf = (unsigned short*)base;
    float* pmp = (float*)(base + (1u << 20));
    float* pmn = (float*)(base + (1u << 20) + (512u << 10));
    float* sqn = (float*)(base + (2u << 20));
    unsigned* cnt = (unsigned*)(base + (2u << 20) + (16u << 10));
    float* accum = (float*)(cnt + 8);  // accum[0]=sum, accum[1]=nvalid

    tl_prep<<<512, 256, 0, stream>>>(E, Ebf, sqn, cnt);
    tl_fused<<<dim3(32, 32), 256, 0, stream>>>(Ebf, labels, sqn, pmp, pmn,
                                               cnt, accum, out);
}

// Round 7
// 85.077 us; speedup vs baseline: 1.8882x; 1.8882x over previous
//
#include <hip/hip_runtime.h>
#include <hip/hip_bf16.h>

// TripletLoss B=4096 D=128 fp32. R7: back to 3 launches (R6's per-block
// agent fence = L2-writeback storm, 1024x). phase1 restructured for
// occupancy: only B staged in LDS (32 KB, xor-swizzled, global_load_lds,
// fine vmcnt + raw barrier); A fragments read directly from global
// (L2-resident Ebf, loads overlap MFMA). 4 blocks/CU (was 2), all 1024
// blocks co-resident. Mine val = sq[j]-2g, LDS-fold (aliasing B buffer),
// atomic-free partial stores; phase2 folds partials, validity from
// sentinels, ticket finalize.

typedef __attribute__((ext_vector_type(8))) short short8;
typedef __attribute__((ext_vector_type(4))) float f32x4;

#define MARGIN_F 0.3f
#define NEG_BIG -3.4e38f
#define POS_BIG 3.4e38f
// gfx9 waitcnt encoding: vmcnt[3:0]|[15:14], expcnt[6:4], lgkmcnt[11:8]
#define WAITVM(N) __builtin_amdgcn_s_waitcnt(((N)&15)|((((N)>>4)&3)<<14)|(7<<4)|(15<<8))

__device__ __forceinline__ void gl_lds16(const void* g, void* l) {
    __builtin_amdgcn_global_load_lds(
        (const __attribute__((address_space(1))) void*)g,
        (__attribute__((address_space(3))) void*)l, 16, 0, 0);
}

__device__ inline unsigned short f2bf(float x) {
    union { __hip_bfloat16 h; unsigned short u; } c;
    c.h = __float2bfloat16(x);
    return c.u;
}

// grid 512 x 256: 32 threads/row. bf16 convert + row norms + zero counters.
__global__ __launch_bounds__(256) void tl_prep(const float* __restrict__ E,
                                               unsigned short* __restrict__ Ebf,
                                               float* __restrict__ sqn,
                                               unsigned* __restrict__ cnt) {
    int t = blockIdx.x * 256 + threadIdx.x;
    if (t < 4) cnt[t] = 0u;
    int row = t >> 5;
    int kq = (t & 31) * 4;
    float4 v = *(const float4*)&E[(size_t)row * 128 + kq];
    float s = fmaf(v.x, v.x, fmaf(v.y, v.y, fmaf(v.z, v.z, v.w * v.w)));
    ushort4 h4;
    h4.x = f2bf(v.x); h4.y = f2bf(v.y); h4.z = f2bf(v.z); h4.w = f2bf(v.w);
    *(ushort4*)&Ebf[(size_t)row * 128 + kq] = h4;
#pragma unroll
    for (int m = 1; m < 32; m <<= 1) s += __shfl_xor(s, m);
    if ((t & 31) == 0) sqn[row] = s;
}

// grid (32,32) x 256. 4 waves 2x2, wave tile 64x64 = 4x4 MFMA 16x16x32.
// LDS: B only, 2 k-chunks of 128 rows x 64 bf16, chunk c of row r at
// column slot c^(r&7) (global_load_lds lane-contiguous AND conflict-free
// ds_read_b128). A frags: direct global_load_dwordx4 (L2-resident).
__global__ __launch_bounds__(256, 4) void tl_phase1(const unsigned short* __restrict__ Ebf,
                                                    const int* __restrict__ labels,
                                                    const float* __restrict__ sqn,
                                                    float* __restrict__ pmp,
                                                    float* __restrict__ pmn) {
    union SM {
        unsigned short B[2][128 * 64];                 // 32 KB
        struct { float mp[128][32]; float mn[128][32]; } f;  // 32 KB
    };
    __shared__ __align__(16) SM sm;

    const int tid = threadIdx.x;
    const int l = tid & 63, w = tid >> 6;
    const int wr = w >> 1, wc = w & 1;
    const int q = l >> 4, r16 = l & 15;
    const int i0 = blockIdx.x * 128, j0 = blockIdx.y * 128;

    // B staging: slot s = w*256 + t2*64 + l; row=s>>3; chunk=(s&7)^(row&7)
    const unsigned short* gB[4];
#pragma unroll
    for (int t2 = 0; t2 < 4; ++t2) {
        int s = w * 256 + t2 * 64 + l;
        int row = s >> 3, ch = (s & 7) ^ (row & 7);
        gB[t2] = Ebf + (size_t)(j0 + row) * 128 + ch * 8;
    }
#pragma unroll
    for (int t2 = 0; t2 < 4; ++t2)
        gl_lds16(gB[t2], &sm.B[0][w * 2048 + t2 * 512]);
#pragma unroll
    for (int t2 = 0; t2 < 4; ++t2)
        gl_lds16(gB[t2] + 64, &sm.B[1][w * 2048 + t2 * 512]);

    // epilogue metadata (independent of staging)
    int li[4][4], lj[4];
    float sj[4];
#pragma unroll
    for (int ti = 0; ti < 4; ++ti)
#pragma unroll
        for (int p = 0; p < 4; ++p)
            li[ti][p] = labels[i0 + wr * 64 + ti * 16 + q * 4 + p];
#pragma unroll
    for (int tj = 0; tj < 4; ++tj) {
        int cj = j0 + wc * 64 + tj * 16 + r16;
        lj[tj] = labels[cj];
        sj[tj] = sqn[cj];
    }

    // A frag base: row = i0 + wr*64 + t2*16 + r16, k = kc*64 + s*32 + q*8
    const unsigned short* aBase = Ebf + (size_t)(i0 + wr * 64 + r16) * 128 + q * 8;

    f32x4 acc[4][4];
#pragma unroll
    for (int ti = 0; ti < 4; ++ti)
#pragma unroll
        for (int tj = 0; tj < 4; ++tj) acc[ti][tj] = (f32x4)0.0f;

#pragma unroll
    for (int kc = 0; kc < 2; ++kc) {
        if (kc == 0) WAITVM(4); else WAITVM(0);
        __builtin_amdgcn_s_barrier();
#pragma unroll
        for (int s = 0; s < 2; ++s) {
            short8 af[4], bf[4];
            const int cA = ((s * 4 + q) ^ (r16 & 7)) * 8;
#pragma unroll
            for (int t2 = 0; t2 < 4; ++t2) {
                af[t2] = *(const short8*)(aBase + (size_t)t2 * 16 * 128 + kc * 64 + s * 32);
                bf[t2] = *(const short8*)&sm.B[kc][(wc * 64 + t2 * 16 + r16) * 64 + cA];
            }
#pragma unroll
            for (int ti = 0; ti < 4; ++ti)
#pragma unroll
                for (int tj = 0; tj < 4; ++tj)
                    acc[ti][tj] = __builtin_amdgcn_mfma_f32_16x16x32_bf16(
                        af[ti], bf[tj], acc[ti][tj], 0, 0, 0);
        }
    }

    // mine val = sq[j] - 2*g (monotone in d2 for fixed i)
    float mp[4][4], mn[4][4];
#pragma unroll
    for (int ti = 0; ti < 4; ++ti)
#pragma unroll
        for (int p = 0; p < 4; ++p) { mp[ti][p] = NEG_BIG; mn[ti][p] = POS_BIG; }
    const bool diagblk = (blockIdx.x == blockIdx.y);
#pragma unroll
    for (int tj = 0; tj < 4; ++tj) {
#pragma unroll
        for (int ti = 0; ti < 4; ++ti)
#pragma unroll
            for (int p = 0; p < 4; ++p) {
                float val = fmaf(-2.0f, acc[ti][tj][p], sj[tj]);
                bool same = (li[ti][p] == lj[tj]);
                bool self = diagblk &&
                    ((wr * 64 + ti * 16 + q * 4 + p) == (wc * 64 + tj * 16 + r16));
                mp[ti][p] = fmaxf(mp[ti][p], (same && !self) ? val : NEG_BIG);
                mn[ti][p] = fminf(mn[ti][p], same ? POS_BIG : val);
            }
    }

    // LDS fold (aliases B buffer): 32 partials/row -> 1 store per row
    __syncthreads();  // all frag reads done before aliasing overwrite
#pragma unroll
    for (int ti = 0; ti < 4; ++ti)
#pragma unroll
        for (int p = 0; p < 4; ++p) {
            int rloc = wr * 64 + ti * 16 + q * 4 + p;
            sm.f.mp[rloc][wc * 16 + r16] = mp[ti][p];
            sm.f.mn[rloc][wc * 16 + r16] = mn[ti][p];
        }
    __syncthreads();
    if (tid < 128) {
        const float4* P = (const float4*)&sm.f.mp[tid][0];
        const float4* N = (const float4*)&sm.f.mn[tid][0];
        float M = NEG_BIG, m_ = POS_BIG;
#pragma unroll
        for (int k = 0; k < 8; ++k) {
            float4 p4 = P[k], n4 = N[k];
            M = fmaxf(M, fmaxf(fmaxf(p4.x, p4.y), fmaxf(p4.z, p4.w)));
            m_ = fminf(m_, fminf(fminf(n4.x, n4.y), fminf(n4.z, n4.w)));
        }
        pmp[(size_t)blockIdx.y * 4096 + i0 + tid] = M;
        pmn[(size_t)blockIdx.y * 4096 + i0 + tid] = m_;
    }
}

// grid 16 x 256: fold 32 partials/row; validity from sentinels; ticket finalize.
__global__ __launch_bounds__(256) void tl_phase2(const float* __restrict__ pmp,
                                                 const float* __restrict__ pmn,
                                                 const float* __restrict__ sqn,
                                                 unsigned* __restrict__ cnt,
                                                 float* __restrict__ accum,
                                                 float* __restrict__ out) {
    __shared__ float sp[4], sv[4];
    int tid = threadIdx.x;
    int r = blockIdx.x * 256 + tid;
    float mp = NEG_BIG, mn = POS_BIG;
#pragma unroll
    for (int k = 0; k < 32; ++k) {
        mp = fmaxf(mp, pmp[(size_t)k * 4096 + r]);
        mn = fminf(mn, pmn[(size_t)k * 4096 + r]);
    }
    float si = sqn[r];
    bool valid = (mp > 0.5f * NEG_BIG) && (mn < 0.5f * POS_BIG);
    float hp = sqrtf(fmaxf(si + mp, 0.0f));
    float hn = sqrtf(fmaxf(si + mn, 0.0f));
    float pr = fmaxf(hp - hn + MARGIN_F, 0.0f);
    float s = valid ? pr : 0.0f;
    float n = valid ? 1.0f : 0.0f;
#pragma unroll
    for (int m = 1; m < 64; m <<= 1) {
        s += __shfl_xor(s, m);
        n += __shfl_xor(n, m);
    }
    if ((tid & 63) == 0) { sp[tid >> 6] = s; sv[tid >> 6] = n; }
    __syncthreads();
    if (tid == 0) {
        atomicAdd(&accum[0], sp[0] + sp[1] + sp[2] + sp[3]);
        atomicAdd(&accum[1], sv[0] + sv[1] + sv[2] + sv[3]);
        __threadfence();
        unsigned tk = atomicAdd(&cnt[2], 1u);
        if (tk == 15u) {
            float a = atomicAdd(&accum[0], 0.0f);  // coherent read
            float b = atomicAdd(&accum[1], 0.0f);
            out[0] = a / fmaxf(b, 1.0f);
        }
    }
}

extern "C" void kernel_launch(void* const* d_in, const int* in_sizes, int n_in,
                              void* d_out, int out_size, void* d_ws, size_t ws_size,
                              hipStream_t stream) {
    const float* E = (const float*)d_in[0];
    const int* labels = (const int*)d_in[1];
    float* out = (float*)d_out;

    // ws: Ebf 1 MB | pmp 512 KB | pmn 512 KB | sqn 16 KB | cnt/accum
    char* base = (char*)d_ws;
    unsigned short* Ebf = (unsigned short*)base;
    float* pmp = (float*)(base + (1u << 20));
    float* pmn = (float*)(base + (1u << 20) + (512u << 10));
    float* sqn = (float*)(base + (2u << 20));
    unsigned* cnt = (unsigned*)(base + (2u << 20) + (16u << 10));
    float* accum = (float*)(cnt + 8);

    tl_prep<<<512, 256, 0, stream>>>(E, Ebf, sqn, cnt);
    tl_phase1<<<dim3(32, 32), 256, 0, stream>>>(Ebf, labels, sqn, pmp, pmn);
    tl_phase2<<<16, 256, 0, stream>>>(pmp, pmn, sqn, cnt, accum, out);
}

// Round 8
// 82.317 us; speedup vs baseline: 1.9515x; 1.0335x over previous
//
#include <hip/hip_runtime.h>
#include <hip/hip_bf16.h>

// TripletLoss B=4096 D=128 fp32. R8: R5 structure (3 launches, both A and B
// LDS-staged) but single-buffered 64-wide K-chunks: 32 KB LDS -> 4 blocks/CU
// (was 2 at 66 KB). Per-kc: sync, issue 16 global_load_lds(16B), vmcnt(0),
// raw s_barrier, 2 MFMA s-steps. Cross-block overlap (4/CU) hides the
// exposed per-chunk load latency. XOR-swizzled LDS: conflict-free b128
// frag reads AND lane-contiguous staging. Epilogue mines val = sq[j]-2g
// (monotone in d2 for fixed i), LDS-fold with 2 threads/row, atomic-free
// partial stores; phase2 folds 32 partials/row, validity from sentinels.

typedef __attribute__((ext_vector_type(8))) short short8;
typedef __attribute__((ext_vector_type(4))) float f32x4;

#define MARGIN_F 0.3f
#define NEG_BIG -3.4e38f
#define POS_BIG 3.4e38f
// gfx9 waitcnt encoding: vmcnt[3:0]|[15:14], expcnt[6:4], lgkmcnt[11:8]
#define WAITVM(N) __builtin_amdgcn_s_waitcnt(((N)&15)|((((N)>>4)&3)<<14)|(7<<4)|(15<<8))

__device__ __forceinline__ void gl_lds16(const void* g, void* l) {
    __builtin_amdgcn_global_load_lds(
        (const __attribute__((address_space(1))) void*)g,
        (__attribute__((address_space(3))) void*)l, 16, 0, 0);
}

__device__ inline unsigned short f2bf(float x) {
    union { __hip_bfloat16 h; unsigned short u; } c;
    c.h = __float2bfloat16(x);
    return c.u;
}

// grid 512 x 256: 32 threads/row. bf16 convert + row norms + zero counters.
__global__ __launch_bounds__(256) void tl_prep(const float* __restrict__ E,
                                               unsigned short* __restrict__ Ebf,
                                               float* __restrict__ sqn,
                                               unsigned* __restrict__ cnt) {
    int t = blockIdx.x * 256 + threadIdx.x;
    if (t < 4) cnt[t] = 0u;
    int row = t >> 5;
    int kq = (t & 31) * 4;
    float4 v = *(const float4*)&E[(size_t)row * 128 + kq];
    float s = fmaf(v.x, v.x, fmaf(v.y, v.y, fmaf(v.z, v.z, v.w * v.w)));
    ushort4 h4;
    h4.x = f2bf(v.x); h4.y = f2bf(v.y); h4.z = f2bf(v.z); h4.w = f2bf(v.w);
    *(ushort4*)&Ebf[(size_t)row * 128 + kq] = h4;
#pragma unroll
    for (int m = 1; m < 32; m <<= 1) s += __shfl_xor(s, m);
    if ((t & 31) == 0) sqn[row] = s;
}

// grid (32,32) x 256. 4 waves 2x2, wave tile 64x64 = 4x4 MFMA 16x16x32.
// LDS per K-chunk: A,B each 128 rows x 64 bf16; chunk c of row r at column
// slot c^(r&7) -> staging is lane-contiguous AND frag b128 reads conflict-free.
__global__ __launch_bounds__(256, 4) void tl_phase1(const unsigned short* __restrict__ Ebf,
                                                    const int* __restrict__ labels,
                                                    const float* __restrict__ sqn,
                                                    float* __restrict__ pmp,
                                                    float* __restrict__ pmn) {
    union SM {
        struct { unsigned short A[128 * 64]; unsigned short B[128 * 64]; } s;  // 32 KB
        struct { float mp[128][32]; float mn[128][32]; } f;                    // 32 KB
    };
    __shared__ __align__(16) SM sm;

    const int tid = threadIdx.x;
    const int l = tid & 63, w = tid >> 6;
    const int wr = w >> 1, wc = w & 1;
    const int q = l >> 4, r16 = l & 15;
    const int i0 = blockIdx.x * 128, j0 = blockIdx.y * 128;

    // staging: slot s = w*256 + t2*64 + l; row=s>>3; chunk=(s&7)^(row&7)
    const unsigned short* gA[4];
    const unsigned short* gB[4];
#pragma unroll
    for (int t2 = 0; t2 < 4; ++t2) {
        int s = w * 256 + t2 * 64 + l;
        int row = s >> 3, ch = (s & 7) ^ (row & 7);
        gA[t2] = Ebf + (size_t)(i0 + row) * 128 + ch * 8;
        gB[t2] = Ebf + (size_t)(j0 + row) * 128 + ch * 8;
    }

    // epilogue metadata (independent of staging)
    int li[4][4], lj[4];
    float sj[4];
#pragma unroll
    for (int ti = 0; ti < 4; ++ti)
#pragma unroll
        for (int p = 0; p < 4; ++p)
            li[ti][p] = labels[i0 + wr * 64 + ti * 16 + q * 4 + p];
#pragma unroll
    for (int tj = 0; tj < 4; ++tj) {
        int cj = j0 + wc * 64 + tj * 16 + r16;
        lj[tj] = labels[cj];
        sj[tj] = sqn[cj];
    }

    f32x4 acc[4][4];
#pragma unroll
    for (int ti = 0; ti < 4; ++ti)
#pragma unroll
        for (int tj = 0; tj < 4; ++tj) acc[ti][tj] = (f32x4)0.0f;

#pragma unroll
    for (int kc = 0; kc < 2; ++kc) {
        __syncthreads();  // all waves done reading LDS from previous chunk
#pragma unroll
        for (int t2 = 0; t2 < 4; ++t2) {
            gl_lds16(gA[t2] + kc * 64, &sm.s.A[w * 2048 + t2 * 512]);
            gl_lds16(gB[t2] + kc * 64, &sm.s.B[w * 2048 + t2 * 512]);
        }
        WAITVM(0);
        __builtin_amdgcn_s_barrier();
#pragma unroll
        for (int s = 0; s < 2; ++s) {
            short8 af[4], bf[4];
            const int cA = ((s * 4 + q) ^ (r16 & 7)) * 8;
#pragma unroll
            for (int t2 = 0; t2 < 4; ++t2) {
                af[t2] = *(const short8*)&sm.s.A[(wr * 64 + t2 * 16 + r16) * 64 + cA];
                bf[t2] = *(const short8*)&sm.s.B[(wc * 64 + t2 * 16 + r16) * 64 + cA];
            }
#pragma unroll
            for (int ti = 0; ti < 4; ++ti)
#pragma unroll
                for (int tj = 0; tj < 4; ++tj)
                    acc[ti][tj] = __builtin_amdgcn_mfma_f32_16x16x32_bf16(
                        af[ti], bf[tj], acc[ti][tj], 0, 0, 0);
        }
    }

    // mine val = sq[j] - 2*g (monotone in d2 for fixed i)
    float mp[4][4], mn[4][4];
#pragma unroll
    for (int ti = 0; ti < 4; ++ti)
#pragma unroll
        for (int p = 0; p < 4; ++p) { mp[ti][p] = NEG_BIG; mn[ti][p] = POS_BIG; }
    const bool diagblk = (blockIdx.x == blockIdx.y);
#pragma unroll
    for (int tj = 0; tj < 4; ++tj) {
#pragma unroll
        for (int ti = 0; ti < 4; ++ti)
#pragma unroll
            for (int p = 0; p < 4; ++p) {
                float val = fmaf(-2.0f, acc[ti][tj][p], sj[tj]);
                bool same = (li[ti][p] == lj[tj]);
                bool self = diagblk &&
                    ((wr * 64 + ti * 16 + q * 4 + p) == (wc * 64 + tj * 16 + r16));
                mp[ti][p] = fmaxf(mp[ti][p], (same && !self) ? val : NEG_BIG);
                mn[ti][p] = fminf(mn[ti][p], same ? POS_BIG : val);
            }
    }

    // LDS fold (aliases staging buffers): 32 partials/row, 2 threads/row
    __syncthreads();  // all frag reads done before aliasing overwrite
#pragma unroll
    for (int ti = 0; ti < 4; ++ti)
#pragma unroll
        for (int p = 0; p < 4; ++p) {
            int rloc = wr * 64 + ti * 16 + q * 4 + p;
            sm.f.mp[rloc][wc * 16 + r16] = mp[ti][p];
            sm.f.mn[rloc][wc * 16 + r16] = mn[ti][p];
        }
    __syncthreads();
    {
        int row = tid >> 1, hf = tid & 1;
        const float4* P = (const float4*)&sm.f.mp[row][hf * 16];
        const float4* N = (const float4*)&sm.f.mn[row][hf * 16];
        float4 p0 = P[0], p1 = P[1], p2 = P[2], p3 = P[3];
        float4 n0 = N[0], n1 = N[1], n2 = N[2], n3 = N[3];
        float M = fmaxf(fmaxf(fmaxf(p0.x, p0.y), fmaxf(p0.z, p0.w)),
                        fmaxf(fmaxf(p1.x, p1.y), fmaxf(p1.z, p1.w)));
        M = fmaxf(M, fmaxf(fmaxf(fmaxf(p2.x, p2.y), fmaxf(p2.z, p2.w)),
                           fmaxf(fmaxf(p3.x, p3.y), fmaxf(p3.z, p3.w))));
        float m_ = fminf(fminf(fminf(n0.x, n0.y), fminf(n0.z, n0.w)),
                         fminf(fminf(n1.x, n1.y), fminf(n1.z, n1.w)));
        m_ = fminf(m_, fminf(fminf(fminf(n2.x, n2.y), fminf(n2.z, n2.w)),
                             fminf(fminf(n3.x, n3.y), fminf(n3.z, n3.w))));
        M = fmaxf(M, __shfl_xor(M, 1));
        m_ = fminf(m_, __shfl_xor(m_, 1));
        if (hf == 0) {
            pmp[(size_t)blockIdx.y * 4096 + i0 + row] = M;
            pmn[(size_t)blockIdx.y * 4096 + i0 + row] = m_;
        }
    }
}

// grid 16 x 256: fold 32 partials/row; validity from sentinels; ticket finalize.
__global__ __launch_bounds__(256) void tl_phase2(const float* __restrict__ pmp,
                                                 const float* __restrict__ pmn,
                                                 const float* __restrict__ sqn,
                                                 unsigned* __restrict__ cnt,
                                                 float* __restrict__ accum,
                                                 float* __restrict__ out) {
    __shared__ float sp[4], sv[4];
    int tid = threadIdx.x;
    int r = blockIdx.x * 256 + tid;
    float mp = NEG_BIG, mn = POS_BIG;
#pragma unroll
    for (int k = 0; k < 32; ++k) {
        mp = fmaxf(mp, pmp[(size_t)k * 4096 + r]);
        mn = fminf(mn, pmn[(size_t)k * 4096 + r]);
    }
    float si = sqn[r];
    bool valid = (mp > 0.5f * NEG_BIG) && (mn < 0.5f * POS_BIG);
    float hp = sqrtf(fmaxf(si + mp, 0.0f));
    float hn = sqrtf(fmaxf(si + mn, 0.0f));
    float pr = fmaxf(hp - hn + MARGIN_F, 0.0f);
    float s = valid ? pr : 0.0f;
    float n = valid ? 1.0f : 0.0f;
#pragma unroll
    for (int m = 1; m < 64; m <<= 1) {
        s += __shfl_xor(s, m);
        n += __shfl_xor(n, m);
    }
    if ((tid & 63) == 0) { sp[tid >> 6] = s; sv[tid >> 6] = n; }
    __syncthreads();
    if (tid == 0) {
        atomicAdd(&accum[0], sp[0] + sp[1] + sp[2] + sp[3]);
        atomicAdd(&accum[1], sv[0] + sv[1] + sv[2] + sv[3]);
        __threadfence();
        unsigned tk = atomicAdd(&cnt[2], 1u);
        if (tk == 15u) {
            float a = atomicAdd(&accum[0], 0.0f);  // coherent read
            float b = atomicAdd(&accum[1], 0.0f);
            out[0] = a / fmaxf(b, 1.0f);
        }
    }
}

extern "C" void kernel_launch(void* const* d_in, const int* in_sizes, int n_in,
                              void* d_out, int out_size, void* d_ws, size_t ws_size,
                              hipStream_t stream) {
    const float* E = (const float*)d_in[0];
    const int* labels = (const int*)d_in[1];
    float* out = (float*)d_out;

    // ws: Ebf 1 MB | pmp 512 KB | pmn 512 KB | sqn 16 KB | cnt/accum
    char* base = (char*)d_ws;
    unsigned short* Ebf = (unsigned short*)base;
    float* pmp = (float*)(base + (1u << 20));
    float* pmn = (float*)(base + (1u << 20) + (512u << 10));
    float* sqn = (float*)(base + (2u << 20));
    unsigned* cnt = (unsigned*)(base + (2u << 20) + (16u << 10));
    float* accum = (float*)(cnt + 8);

    tl_prep<<<512, 256, 0, stream>>>(E, Ebf, sqn, cnt);
    tl_phase1<<<dim3(32, 32), 256, 0, stream>>>(Ebf, labels, sqn, pmp, pmn);
    tl_phase2<<<16, 256, 0, stream>>>(pmp, pmn, sqn, cnt, accum, out);
}